// Round 1
// baseline (3315.847 us; speedup 1.0000x reference)
//
#include <hip/hip_runtime.h>

#define HID 50
#define LAT 16

__device__ __forceinline__ float fast_tanh(float x) {
    // tanh(x) = 1 - 2/(exp(2x)+1); v_exp + v_rcp, saturates correctly at +/-inf
    float e = __expf(2.0f * x);
    return 1.0f - 2.0f * __builtin_amdgcn_rcpf(e + 1.0f);
}

// o = tanh(zin @ Wo1 + bo1) @ Wo2 + bo2   (one batch element, all in registers)
__device__ __forceinline__ void odef(const float* __restrict__ Wo1, const float* __restrict__ bo1,
                                     const float* __restrict__ Wo2, const float* __restrict__ bo2,
                                     const float zin[LAT], float o[LAT]) {
    float h[HID];
#pragma unroll
    for (int j = 0; j < HID; j++) h[j] = bo1[j];
#pragma unroll
    for (int i = 0; i < LAT; i++) {
        float zi = zin[i];
#pragma unroll
        for (int j = 0; j < HID; j++) h[j] = __builtin_fmaf(zi, Wo1[i * HID + j], h[j]);
    }
#pragma unroll
    for (int k = 0; k < LAT; k++) o[k] = bo2[k];
#pragma unroll
    for (int j = 0; j < HID; j++) {
        float hj = fast_tanh(h[j]);
#pragma unroll
        for (int k = 0; k < LAT; k++) o[k] = __builtin_fmaf(hj, Wo2[j * LAT + k], o[k]);
    }
}

// y = relu(z @ Wd1 + bd1) @ Wd2 + bd2  (scalar output)
__device__ __forceinline__ float decode(const float* __restrict__ Wd1, const float* __restrict__ bd1,
                                        const float* __restrict__ Wd2, const float* __restrict__ bd2,
                                        const float z[LAT]) {
    float h[HID];
#pragma unroll
    for (int j = 0; j < HID; j++) h[j] = bd1[j];
#pragma unroll
    for (int i = 0; i < LAT; i++) {
        float zi = z[i];
#pragma unroll
        for (int j = 0; j < HID; j++) h[j] = __builtin_fmaf(zi, Wd1[i * HID + j], h[j]);
    }
    float y = bd2[0];
#pragma unroll
    for (int j = 0; j < HID; j++) y = __builtin_fmaf(fmaxf(h[j], 0.0f), Wd2[j], y);
    return y;
}

__global__ void __launch_bounds__(256, 1)
node_kernel(const float* __restrict__ x0, const float* __restrict__ t,
            const float* __restrict__ We1, const float* __restrict__ be1,
            const float* __restrict__ We2, const float* __restrict__ be2,
            const float* __restrict__ Wo1, const float* __restrict__ bo1,
            const float* __restrict__ Wo2, const float* __restrict__ bo2,
            const float* __restrict__ Wd1, const float* __restrict__ bd1,
            const float* __restrict__ Wd2, const float* __restrict__ bd2,
            float* __restrict__ out, int B, int T) {
    int b = blockIdx.x * blockDim.x + threadIdx.x;
    if (b >= B) return;

    // ---- Encoder: z = relu(x0 @ We1 + be1) @ We2 + be2 ----
    float xa = x0[2 * b], xb = x0[2 * b + 1];
    float z[LAT];
#pragma unroll
    for (int k = 0; k < LAT; k++) z[k] = be2[k];
#pragma unroll
    for (int j = 0; j < HID; j++) {
        float h = __builtin_fmaf(xa, We1[j], __builtin_fmaf(xb, We1[HID + j], be1[j]));
        h = fmaxf(h, 0.0f);
#pragma unroll
        for (int k = 0; k < LAT; k++) z[k] = __builtin_fmaf(h, We2[j * LAT + k], z[k]);
    }

    // t = 0 output
    out[b] = decode(Wd1, bd1, Wd2, bd2, z);

    // ---- RK4 time stepping ----
    for (int s = 0; s < T - 1; s++) {
        float dt = t[s + 1] - t[s];
        float ksum[LAT], ktmp[LAT], ztmp[LAT];

        odef(Wo1, bo1, Wo2, bo2, z, ktmp);  // k1
#pragma unroll
        for (int i = 0; i < LAT; i++) {
            ksum[i] = ktmp[i];
            ztmp[i] = __builtin_fmaf(0.5f * dt, ktmp[i], z[i]);
        }
        odef(Wo1, bo1, Wo2, bo2, ztmp, ktmp);  // k2
#pragma unroll
        for (int i = 0; i < LAT; i++) {
            ksum[i] = __builtin_fmaf(2.0f, ktmp[i], ksum[i]);
            ztmp[i] = __builtin_fmaf(0.5f * dt, ktmp[i], z[i]);
        }
        odef(Wo1, bo1, Wo2, bo2, ztmp, ktmp);  // k3
#pragma unroll
        for (int i = 0; i < LAT; i++) {
            ksum[i] = __builtin_fmaf(2.0f, ktmp[i], ksum[i]);
            ztmp[i] = __builtin_fmaf(dt, ktmp[i], z[i]);
        }
        odef(Wo1, bo1, Wo2, bo2, ztmp, ktmp);  // k4
        float c = dt * (1.0f / 6.0f);
#pragma unroll
        for (int i = 0; i < LAT; i++) z[i] = __builtin_fmaf(c, ksum[i] + ktmp[i], z[i]);

        out[(size_t)(s + 1) * B + b] = decode(Wd1, bd1, Wd2, bd2, z);
    }
}

extern "C" void kernel_launch(void* const* d_in, const int* in_sizes, int n_in,
                              void* d_out, int out_size, void* d_ws, size_t ws_size,
                              hipStream_t stream) {
    const float* x0  = (const float*)d_in[0];
    const float* t   = (const float*)d_in[1];
    const float* We1 = (const float*)d_in[2];
    const float* be1 = (const float*)d_in[3];
    const float* We2 = (const float*)d_in[4];
    const float* be2 = (const float*)d_in[5];
    const float* Wo1 = (const float*)d_in[6];
    const float* bo1 = (const float*)d_in[7];
    const float* Wo2 = (const float*)d_in[8];
    const float* bo2 = (const float*)d_in[9];
    const float* Wd1 = (const float*)d_in[10];
    const float* bd1 = (const float*)d_in[11];
    const float* Wd2 = (const float*)d_in[12];
    const float* bd2 = (const float*)d_in[13];
    float* out = (float*)d_out;

    int B = in_sizes[0] / 2;   // 65536
    int T = in_sizes[1];       // 100

    dim3 block(256);
    dim3 grid((B + 255) / 256);
    hipLaunchKernelGGL(node_kernel, grid, block, 0, stream,
                       x0, t, We1, be1, We2, be2, Wo1, bo1, Wo2, bo2,
                       Wd1, bd1, Wd2, bd2, out, B, T);
}